// Round 5
// baseline (214.591 us; speedup 1.0000x reference)
//
#include <hip/hip_runtime.h>

#define OBS_LEN 8
#define PRED_LEN 12
#define TILE_B 32
#define NTHREADS 256

typedef __attribute__((ext_vector_type(8))) short short8;  // 8 bf16
typedef __attribute__((ext_vector_type(4))) float floatx4;
typedef __attribute__((ext_vector_type(2))) float floatx2;
typedef __attribute__((ext_vector_type(2))) unsigned int u32x2;
typedef unsigned short u16;
typedef unsigned int u32;

#define L2E 1.442695040888963f

__device__ __forceinline__ u16 f2bf(float f) {
  __bf16 b = (__bf16)f;
  return __builtin_bit_cast(u16, b);
}

#if __has_builtin(__builtin_amdgcn_exp2f)
__device__ __forceinline__ float fexp2_(float x) { return __builtin_amdgcn_exp2f(x); }
#else
__device__ __forceinline__ float fexp2_(float x) { return exp2f(x); }
#endif
__device__ __forceinline__ floatx2 exp2v(floatx2 x) {
  floatx2 r;
  r.x = fexp2_(x.x);
  r.y = fexp2_(x.y);
  return r;
}
#if __has_builtin(__builtin_amdgcn_rcpf)
__device__ __forceinline__ floatx2 rcp2(floatx2 x) {  // raw v_rcp ~1ulp
  floatx2 r;
  r.x = __builtin_amdgcn_rcpf(x.x);
  r.y = __builtin_amdgcn_rcpf(x.y);
  return r;
}
#else
__device__ __forceinline__ floatx2 rcp2(floatx2 x) {
  return floatx2{1.0f / x.x, 1.0f / x.y};
}
#endif

__device__ __forceinline__ floatx4 mfma_bf(short8 a, short8 b, floatx4 c) {
  return __builtin_amdgcn_mfma_f32_16x16x32_bf16(a, b, c, 0, 0, 0);
}

// A-operand fragments (A[m=lane&15][k=quad*8+j]) for this wave's 4 gate tiles
// (gate = t*64 + u0 + l16), weights rounded to bf16 = the ref's operand rounding.
__device__ __forceinline__ void load_afrags(const float* __restrict__ W,
                                            short8 (&af)[4][2],
                                            int u0, int q, int l16) {
#pragma unroll
  for (int t = 0; t < 4; ++t)
#pragma unroll
    for (int kf = 0; kf < 2; ++kf) {
      const float* src = W + (t * 64 + u0 + l16) * 64 + kf * 32 + q * 8;
      const floatx4 w0 = *(const floatx4*)src;
      const floatx4 w1 = *(const floatx4*)(src + 4);
      short8 a;
#pragma unroll
      for (int j = 0; j < 4; ++j) {
        a[j] = (short)f2bf(w0[j]);
        a[j + 4] = (short)f2bf(w1[j]);
      }
      af[t][kf] = a;
    }
}

// Folded decoder weights: W_eff[g,u] = W_hh[g,u] + A0[g]*h2p[0,u] + A1[g]*h2p[1,u]
// (rank-2 update, f32 math, ONE bf16 rounding at the end).
__device__ __forceinline__ void load_afrags_eff(const float* __restrict__ Whh,
                                                const float* __restrict__ aS0,
                                                const float* __restrict__ aS1,
                                                const float* __restrict__ hw0,
                                                const float* __restrict__ hw1,
                                                short8 (&af)[4][2],
                                                int u0, int q, int l16) {
#pragma unroll
  for (int t = 0; t < 4; ++t) {
    const int g = t * 64 + u0 + l16;
    const float a0 = aS0[g], a1 = aS1[g];
#pragma unroll
    for (int kf = 0; kf < 2; ++kf) {
      const int u = kf * 32 + q * 8;
      const float* src = Whh + g * 64 + u;
      const floatx4 w0 = *(const floatx4*)src;
      const floatx4 w1 = *(const floatx4*)(src + 4);
      const floatx4 p00 = *(const floatx4*)(hw0 + u);
      const floatx4 p01 = *(const floatx4*)(hw0 + u + 4);
      const floatx4 p10 = *(const floatx4*)(hw1 + u);
      const floatx4 p11 = *(const floatx4*)(hw1 + u + 4);
      short8 a;
#pragma unroll
      for (int j = 0; j < 4; ++j) {
        a[j] = (short)f2bf(w0[j] + a0 * p00[j] + a1 * p10[j]);
        a[j + 4] = (short)f2bf(w1[j] + a0 * p01[j] + a1 * p11[j]);
      }
      af[t][kf] = a;
    }
  }
}

// Rank-2 input fold for gate row g: A_r[g] = sum_e W_ih[g,e]*emb_w[e,r],
// B0[g] = sum_e W_ih[g,e]*emb_b[e]. Collapses the whole x-path (x is a
// linear image of the 2-dim input) into 2 scalars/gate + bias.
__device__ __forceinline__ void fold_rank2(const float* __restrict__ wr,
                                           const float* __restrict__ emb_w,
                                           const float* __restrict__ emb_b,
                                           float& A0, float& A1, float& B0) {
  A0 = A1 = B0 = 0.f;
#pragma unroll
  for (int e4 = 0; e4 < 16; ++e4) {
    const floatx4 w = *(const floatx4*)(wr + e4 * 4);
    const floatx4 m0 = *(const floatx4*)(emb_w + e4 * 8);      // e0,e1 pairs
    const floatx4 m1 = *(const floatx4*)(emb_w + e4 * 8 + 4);  // e2,e3 pairs
    const floatx4 bb = *(const floatx4*)(emb_b + e4 * 4);
    A0 += w[0] * m0[0] + w[1] * m0[2] + w[2] * m1[0] + w[3] * m1[2];
    A1 += w[0] * m0[1] + w[1] * m0[3] + w[2] * m1[1] + w[3] * m1[3];
    B0 += w[0] * bb[0] + w[1] * bb[1] + w[2] * bb[2] + w[3] * bb[3];
  }
}

// Pos-term A-fragment: column k=0 holds A0[g], k=1 holds A1[g], rest zero.
// Used as mfma(xf, posfrag, bias) -> adds p0*A0[g]+p1*A1[g] on the matrix pipe.
__device__ __forceinline__ void build_gfrag(const float* __restrict__ A0t,
                                            const float* __restrict__ A1t,
                                            short8 (&xf)[4],
                                            int u0, int q, int l16) {
#pragma unroll
  for (int t = 0; t < 4; ++t) {
    short8 a = short8{0, 0, 0, 0, 0, 0, 0, 0};
    if (q == 0) {
      const int g = t * 64 + u0 + l16;
      a[0] = (short)f2bf(A0t[g]);
      a[1] = (short)f2bf(A1t[g]);
    }
    xf[t] = a;
  }
}

// Gate nonlinearity + swizzled h write for one 16x16 tile (verbatim math from
// the proven kernel; c2 = running cell state for this n-tile).
__device__ __forceinline__ void nonlin_store(const floatx4 (&acc)[4],
                                             floatx2 (&c2)[2],
                                             u16* __restrict__ wrh,
                                             int s, int q, int wv) {
  const int sw = s & 7;
  u32 hpk[2];
#pragma unroll
  for (int p = 0; p < 2; ++p) {
    const floatx2 iv = {acc[0][2 * p], acc[0][2 * p + 1]};
    const floatx2 fv = {acc[1][2 * p], acc[1][2 * p + 1]};
    const floatx2 gv = {acc[2][2 * p], acc[2][2 * p + 1]};
    const floatx2 ov = {acc[3][2 * p], acc[3][2 * p + 1]};
    const floatx2 ei = exp2v(iv * -L2E);
    const floatx2 ef = exp2v(fv * -L2E);
    const floatx2 eg = exp2v(gv * (2.0f * L2E));
    const floatx2 eo = exp2v(ov * -L2E);
    const floatx2 A = ei + 1.0f;   // 1/sig(i)
    const floatx2 F = ef + 1.0f;   // 1/sig(f)
    const floatx2 Bg = eg + 1.0f;  // tanh(g) = (eg-1)/Bg
    const floatx2 P = A * Bg;
    const floatx2 num = c2[p] * P + (eg - 1.0f) * F;
    const floatx2 cn = num * rcp2(F * P);
    c2[p] = cn;
    const floatx2 ec = exp2v(cn * (2.0f * L2E));
    const floatx2 h = (ec - 1.0f) * rcp2((eo + 1.0f) * (ec + 1.0f));
    hpk[p] = (u32)f2bf(h.x) | ((u32)f2bf(h.y) << 16);
  }
  *(u32x2*)(wrh + s * 64 + (((wv * 2 + (q >> 1)) ^ sw) * 8) + (q & 1) * 4) =
      u32x2{hpk[0], hpk[1]};
}

// One fully-folded cell step: gates = h @ W_hh^T + (p0*A0 + p1*A1 + bias).
// Pos term via 1 extra MFMA per gate-group (zero-padded K) -- matrix pipe,
// independent of the h ds_reads so it issues first. 12 MFMAs per n-tile.
__device__ __forceinline__ void cell_step_fold(
    const u16* __restrict__ rdh, u16* __restrict__ wrh,
    const short8 (&afh)[4][2], const short8 (&xf)[4],
    const float* __restrict__ biasrow, const float* __restrict__ posrow,
    floatx2 (&c)[2][2], int q, int l16, int wv, int u0) {
#pragma unroll
  for (int n = 0; n < 2; ++n) {
    const int s = n * 16 + l16, sw = s & 7;
    const u16* hr = rdh + s * 64;
    const short8 hb0 = *(const short8*)(hr + ((q ^ sw) * 8));
    const short8 hb1 = *(const short8*)(hr + (((q + 4) ^ sw) * 8));
    const floatx2 pp = *(const floatx2*)(posrow + s * 2);
    short8 pf = short8{0, 0, 0, 0, 0, 0, 0, 0};
    if (q == 0) {
      pf[0] = (short)f2bf(pp.x);
      pf[1] = (short)f2bf(pp.y);
    }
    floatx4 acc[4];
#pragma unroll
    for (int t = 0; t < 4; ++t) {
      const floatx4 bias = *(const floatx4*)(biasrow + t * 64 + u0 + q * 4);
      acc[t] = mfma_bf(xf[t], pf, bias);  // pos term, no h dependence
    }
#pragma unroll
    for (int t = 0; t < 4; ++t) acc[t] = mfma_bf(afh[t][0], hb0, acc[t]);
#pragma unroll
    for (int t = 0; t < 4; ++t) acc[t] = mfma_bf(afh[t][1], hb1, acc[t]);
    nonlin_store(acc, c[n], wrh, s, q, wv);
  }
}

// Folded decoder step (j>=1): gates = h @ W_eff^T + b_eff (K=64, 8 MFMAs/n).
// n-loop with acc[4] (not acc[2][4]) to cap peak regs; 4 blocks/CU TLP covers
// the ILP loss. rel_{j-1} via 2 MFMAs on xf[0..1] (rows 0/1 = h2p rows):
// wave n covers tile n. rel -> LDS (no vmcnt drain at barriers).
__device__ __forceinline__ void dec_step_folded(
    const u16* __restrict__ rdh, u16* __restrict__ wrh,
    const short8 (&af)[4][2], const short8 (&xf)[4],
    const float* __restrict__ biasrow, float b2p0, float b2p1,
    float* __restrict__ relrow,
    floatx2 (&c)[2][2], int q, int l16, int wv, int u0) {
#pragma unroll
  for (int n = 0; n < 2; ++n) {
    const int s = n * 16 + l16, sw = s & 7;
    const u16* hr = rdh + s * 64;
    const short8 hb0 = *(const short8*)(hr + ((q ^ sw) * 8));
    const short8 hb1 = *(const short8*)(hr + (((q + 4) ^ sw) * 8));
    floatx4 acc[4];
#pragma unroll
    for (int t = 0; t < 4; ++t) {
      const floatx4 bias = *(const floatx4*)(biasrow + t * 64 + u0 + q * 4);
      acc[t] = mfma_bf(af[t][0], hb0, bias);
    }
#pragma unroll
    for (int t = 0; t < 4; ++t) acc[t] = mfma_bf(af[t][1], hb1, acc[t]);
    if (wv == n) {  // 2 rel MFMAs on the idle matrix pipe; rows 0,1 -> q==0
      floatx4 ar = mfma_bf(xf[0], hb0, floatx4{0.f, 0.f, 0.f, 0.f});
      ar = mfma_bf(xf[1], hb1, ar);
      if (q == 0)
        *(floatx2*)(relrow + s * 2) = floatx2{ar[0] + b2p0, ar[1] + b2p1};
    }
    nonlin_store(acc, c[n], wrh, s, q, wv);
  }
}

// (256,4): 16 waves/CU, 4 blocks/CU, 128 VGPR/wave budget. R4 spilled ~16
// dwords/thread (WRITE_SIZE 6->39MB): persistent accum demand was
// afh(32)+gf(16)+afp(8)=56, +acc(16) transient = 72 > 64 accum half.
// Fix: gf and afp share ONE xf[4] array (disjoint lifetimes: pos-term frags
// die exactly when the rel frags are born) -> persistent 48, peak 64 = fits.
__global__ void __launch_bounds__(NTHREADS, 4)
lstm_kernel(const float* __restrict__ obs_rel,
            const float* __restrict__ enc_emb_w, const float* __restrict__ enc_emb_b,
            const float* __restrict__ enc_w_ih, const float* __restrict__ enc_w_hh,
            const float* __restrict__ enc_b_ih, const float* __restrict__ enc_b_hh,
            const float* __restrict__ dec_emb_w, const float* __restrict__ dec_emb_b,
            const float* __restrict__ dec_w_ih, const float* __restrict__ dec_w_hh,
            const float* __restrict__ dec_b_ih, const float* __restrict__ dec_b_hh,
            const float* __restrict__ h2p_w, const float* __restrict__ h2p_b,
            float* __restrict__ out, int batch) {
  __shared__ __align__(16) u16 hS[2][TILE_B * 64];
  __shared__ __align__(16) float posS[OBS_LEN][TILE_B * 2];
  __shared__ __align__(16) float biasS[3][256];  // enc, dec0, dec-folded (f32)
  __shared__ __align__(16) float eA0[256], eA1[256];  // encoder rank-2 factors
  __shared__ __align__(16) float dA0[256], dA1[256];  // decoder rank-2 factors
  __shared__ __align__(16) float hw0S[64], hw1S[64];  // h2p_w rows, f32
  __shared__ __align__(16) float relS[PRED_LEN][TILE_B * 2];  // rel staging

  const int tid = threadIdx.x;
  const int wv = tid >> 6, lane = tid & 63;
  const int q = lane >> 4, l16 = lane & 15;
  const int u0 = wv << 4;
  const long S0 = (long)blockIdx.x * TILE_B;

  if (tid < 128) {  // stage all 8 encoder-step position rows (coalesced)
    const int t = tid >> 4, i = tid & 15;
    *(floatx4*)&posS[t][i * 4] =
        *(const floatx4*)(obs_rel + (long)t * batch * 2 + S0 * 2 + i * 4);
  }
  if (tid < 64) {
    hw0S[tid] = h2p_w[tid];        // f32: W_eff build + rel-frag source
    hw1S[tid] = h2p_w[64 + tid];
  }
  {
    float A0, A1, B0;
    fold_rank2(enc_w_ih + tid * 64, enc_emb_w, enc_emb_b, A0, A1, B0);
    eA0[tid] = A0;
    eA1[tid] = A1;
    biasS[0][tid] = enc_b_ih[tid] + enc_b_hh[tid] + B0;
    fold_rank2(dec_w_ih + tid * 64, dec_emb_w, dec_emb_b, A0, A1, B0);
    dA0[tid] = A0;
    dA1[tid] = A1;
    const float db = dec_b_ih[tid] + dec_b_hh[tid] + B0;
    biasS[1][tid] = db;                                   // dec step 0
    biasS[2][tid] = db + A0 * h2p_b[0] + A1 * h2p_b[1];   // folded steps
  }
  for (int i = tid; i < TILE_B * 64 / 2; i += NTHREADS) ((u32*)&hS[0][0])[i] = 0;

  short8 afh[4][2], xf[4];   // xf = gf (enc/dec0) then afp (decoder rel)
  floatx2 c[2][2];
  load_afrags(enc_w_hh, afh, u0, q, l16);
  c[0][0] = c[0][1] = c[1][0] = c[1][1] = floatx2{0.f, 0.f};
  const float b2p0 = h2p_b[0], b2p1 = h2p_b[1];
  __syncthreads();  // posS + tables + bias + fold factors + h0 visible
  build_gfrag(eA0, eA1, xf, u0, q, l16);

  int pb = 0;
#pragma unroll 1
  for (int t = 0; t < OBS_LEN; ++t) {
    cell_step_fold(hS[pb], hS[pb ^ 1], afh, xf, &biasS[0][0], &posS[t][0], c,
                   q, l16, wv, u0);
    __syncthreads();
    pb ^= 1;
  }

  // ---- decoder step 0: x0 = lin(pos7) folded with dec tables, c reset
  load_afrags(dec_w_hh, afh, u0, q, l16);
  build_gfrag(dA0, dA1, xf, u0, q, l16);
  c[0][0] = c[0][1] = c[1][0] = c[1][1] = floatx2{0.f, 0.f};
  cell_step_fold(hS[pb], hS[pb ^ 1], afh, xf, &biasS[1][0], &posS[7][0], c,
                 q, l16, wv, u0);
  // rebuild afh as W_eff fragments for the h-feedback fold
  load_afrags_eff(dec_w_hh, dA0, dA1, hw0S, hw1S, afh, u0, q, l16);
  // xf[0..1] become the rel A-fragment: rows 0/1 = h2p rows (bf16), rest 0
#pragma unroll
  for (int kf = 0; kf < 2; ++kf) {
    const int kb = kf * 32 + q * 8;
    short8 a;
#pragma unroll
    for (int j = 0; j < 4; ++j) {
      const float r0 = (l16 == 0) ? hw0S[kb + j] : (l16 == 1) ? hw1S[kb + j] : 0.f;
      const float r1 =
          (l16 == 0) ? hw0S[kb + 4 + j] : (l16 == 1) ? hw1S[kb + 4 + j] : 0.f;
      a[j] = (short)f2bf(r0);
      a[j + 4] = (short)f2bf(r1);
    }
    xf[kf] = a;
  }
  __syncthreads();
  pb ^= 1;

  // ---- folded decoder steps 1..11: one barrier each; rel_{j-1} via MFMA
#pragma unroll 1
  for (int j = 1; j < PRED_LEN; ++j) {
    dec_step_folded(hS[pb], hS[pb ^ 1], afh, xf, &biasS[2][0], b2p0, b2p1,
                    &relS[j - 1][0], c, q, l16, wv, u0);
    __syncthreads();  // h_{j+1} ready; hS[pb] reads done before next overwrite
    pb ^= 1;
  }

  // ---- trailing output: rel_pos[11] from h_12 (2 MFMAs on waves 0/1)
  if (wv < 2) {
    const int s = wv * 16 + l16, sw = s & 7;
    const u16* hr = hS[pb] + s * 64;
    const short8 ha = *(const short8*)(hr + ((q ^ sw) * 8));
    const short8 hc = *(const short8*)(hr + (((q + 4) ^ sw) * 8));
    floatx4 ar = mfma_bf(xf[0], ha, floatx4{0.f, 0.f, 0.f, 0.f});
    ar = mfma_bf(xf[1], hc, ar);
    if (q == 0)
      *(floatx2*)(&relS[PRED_LEN - 1][s * 2]) =
          floatx2{ar[0] + b2p0, ar[1] + b2p1};
  }
  __syncthreads();

  // ---- flush relS -> out, fully coalesced (3 f32/thread)
#pragma unroll
  for (int r = 0; r < 3; ++r) {
    const int f = tid + r * 256;          // 0..767 = 12 rows x 64 f32
    const int j = f >> 6, e = f & 63;
    out[(long)j * batch * 2 + S0 * 2 + e] = ((const float*)relS)[f];
  }
}

extern "C" void kernel_launch(void* const* d_in, const int* in_sizes, int n_in,
                              void* d_out, int out_size, void* d_ws, size_t ws_size,
                              hipStream_t stream) {
  const float* obs_rel = (const float*)d_in[1];
  const int batch = in_sizes[1] / (OBS_LEN * 2);  // 65536

  const int blocks = batch / TILE_B;  // 2048
  hipLaunchKernelGGL(lstm_kernel, dim3(blocks), dim3(NTHREADS), 0, stream,
                     obs_rel,
                     (const float*)d_in[2], (const float*)d_in[3],
                     (const float*)d_in[4], (const float*)d_in[5],
                     (const float*)d_in[6], (const float*)d_in[7],
                     (const float*)d_in[8], (const float*)d_in[9],
                     (const float*)d_in[10], (const float*)d_in[11],
                     (const float*)d_in[12], (const float*)d_in[13],
                     (const float*)d_in[14], (const float*)d_in[15],
                     (float*)d_out, batch);
}

// Round 6
// 200.046 us; speedup vs baseline: 1.0727x; 1.0727x over previous
//
#include <hip/hip_runtime.h>

#define OBS_LEN 8
#define PRED_LEN 12
#define TILE_B 64
#define NTHREADS 256

typedef __attribute__((ext_vector_type(8))) short short8;  // 8 bf16
typedef __attribute__((ext_vector_type(4))) float floatx4;
typedef __attribute__((ext_vector_type(2))) float floatx2;
typedef __attribute__((ext_vector_type(2))) unsigned int u32x2;
typedef unsigned short u16;
typedef unsigned int u32;

#define L2E 1.442695040888963f

__device__ __forceinline__ u16 f2bf(float f) {
  __bf16 b = (__bf16)f;
  return __builtin_bit_cast(u16, b);
}

#if __has_builtin(__builtin_amdgcn_exp2f)
__device__ __forceinline__ float fexp2_(float x) { return __builtin_amdgcn_exp2f(x); }
#else
__device__ __forceinline__ float fexp2_(float x) { return exp2f(x); }
#endif
__device__ __forceinline__ floatx2 exp2v(floatx2 x) {
  floatx2 r;
  r.x = fexp2_(x.x);
  r.y = fexp2_(x.y);
  return r;
}
#if __has_builtin(__builtin_amdgcn_rcpf)
__device__ __forceinline__ floatx2 rcp2(floatx2 x) {  // raw v_rcp ~1ulp
  floatx2 r;
  r.x = __builtin_amdgcn_rcpf(x.x);
  r.y = __builtin_amdgcn_rcpf(x.y);
  return r;
}
#else
__device__ __forceinline__ floatx2 rcp2(floatx2 x) {
  return floatx2{1.0f / x.x, 1.0f / x.y};
}
#endif

__device__ __forceinline__ floatx4 mfma_bf(short8 a, short8 b, floatx4 c) {
  return __builtin_amdgcn_mfma_f32_16x16x32_bf16(a, b, c, 0, 0, 0);
}

// A-operand fragments (A[m=lane&15][k=quad*8+j]) for this wave's 4 gate tiles
// (gate = t*64 + u0 + l16), weights rounded to bf16 = the ref's operand rounding.
__device__ __forceinline__ void load_afrags(const float* __restrict__ W,
                                            short8 (&af)[4][2],
                                            int u0, int q, int l16) {
#pragma unroll
  for (int t = 0; t < 4; ++t)
#pragma unroll
    for (int kf = 0; kf < 2; ++kf) {
      const float* src = W + (t * 64 + u0 + l16) * 64 + kf * 32 + q * 8;
      const floatx4 w0 = *(const floatx4*)src;
      const floatx4 w1 = *(const floatx4*)(src + 4);
      short8 a;
#pragma unroll
      for (int j = 0; j < 4; ++j) {
        a[j] = (short)f2bf(w0[j]);
        a[j + 4] = (short)f2bf(w1[j]);
      }
      af[t][kf] = a;
    }
}

// Folded decoder weights: W_eff[g,u] = W_hh[g,u] + A0[g]*h2p[0,u] + A1[g]*h2p[1,u]
// (rank-2 update, f32 math, ONE bf16 rounding at the end).
__device__ __forceinline__ void load_afrags_eff(const float* __restrict__ Whh,
                                                const float* __restrict__ aS0,
                                                const float* __restrict__ aS1,
                                                const float* __restrict__ hw0,
                                                const float* __restrict__ hw1,
                                                short8 (&af)[4][2],
                                                int u0, int q, int l16) {
#pragma unroll
  for (int t = 0; t < 4; ++t) {
    const int g = t * 64 + u0 + l16;
    const float a0 = aS0[g], a1 = aS1[g];
#pragma unroll
    for (int kf = 0; kf < 2; ++kf) {
      const int u = kf * 32 + q * 8;
      const float* src = Whh + g * 64 + u;
      const floatx4 w0 = *(const floatx4*)src;
      const floatx4 w1 = *(const floatx4*)(src + 4);
      const floatx4 p00 = *(const floatx4*)(hw0 + u);
      const floatx4 p01 = *(const floatx4*)(hw0 + u + 4);
      const floatx4 p10 = *(const floatx4*)(hw1 + u);
      const floatx4 p11 = *(const floatx4*)(hw1 + u + 4);
      short8 a;
#pragma unroll
      for (int j = 0; j < 4; ++j) {
        a[j] = (short)f2bf(w0[j] + a0 * p00[j] + a1 * p10[j]);
        a[j + 4] = (short)f2bf(w1[j] + a0 * p01[j] + a1 * p11[j]);
      }
      af[t][kf] = a;
    }
  }
}

// Rank-2 input fold for gate row g: A_r[g] = sum_e W_ih[g,e]*emb_w[e,r],
// B0[g] = sum_e W_ih[g,e]*emb_b[e]. Collapses the whole x-path (x is a
// linear image of the 2-dim input) into 2 scalars/gate + bias.
__device__ __forceinline__ void fold_rank2(const float* __restrict__ wr,
                                           const float* __restrict__ emb_w,
                                           const float* __restrict__ emb_b,
                                           float& A0, float& A1, float& B0) {
  A0 = A1 = B0 = 0.f;
#pragma unroll
  for (int e4 = 0; e4 < 16; ++e4) {
    const floatx4 w = *(const floatx4*)(wr + e4 * 4);
    const floatx4 m0 = *(const floatx4*)(emb_w + e4 * 8);      // e0,e1 pairs
    const floatx4 m1 = *(const floatx4*)(emb_w + e4 * 8 + 4);  // e2,e3 pairs
    const floatx4 bb = *(const floatx4*)(emb_b + e4 * 4);
    A0 += w[0] * m0[0] + w[1] * m0[2] + w[2] * m1[0] + w[3] * m1[2];
    A1 += w[0] * m0[1] + w[1] * m0[3] + w[2] * m1[1] + w[3] * m1[3];
    B0 += w[0] * bb[0] + w[1] * bb[1] + w[2] * bb[2] + w[3] * bb[3];
  }
}

// Pos-term A-fragment: column k=0 holds A0[g], k=1 holds A1[g], rest zero.
// Used as mfma(xf, posfrag, bias) -> adds p0*A0[g]+p1*A1[g] on the matrix pipe.
__device__ __forceinline__ void build_gfrag(const float* __restrict__ A0t,
                                            const float* __restrict__ A1t,
                                            short8 (&xf)[4],
                                            int u0, int q, int l16) {
#pragma unroll
  for (int t = 0; t < 4; ++t) {
    short8 a = short8{0, 0, 0, 0, 0, 0, 0, 0};
    if (q == 0) {
      const int g = t * 64 + u0 + l16;
      a[0] = (short)f2bf(A0t[g]);
      a[1] = (short)f2bf(A1t[g]);
    }
    xf[t] = a;
  }
}

// Gate nonlinearity + swizzled h write for one 16x16 tile (verbatim math from
// the proven kernel; c2 = running cell state for this n-tile).
__device__ __forceinline__ void nonlin_store(const floatx4 (&acc)[4],
                                             floatx2 (&c2)[2],
                                             u16* __restrict__ wrh,
                                             int s, int q, int wv) {
  const int sw = s & 7;
  u32 hpk[2];
#pragma unroll
  for (int p = 0; p < 2; ++p) {
    const floatx2 iv = {acc[0][2 * p], acc[0][2 * p + 1]};
    const floatx2 fv = {acc[1][2 * p], acc[1][2 * p + 1]};
    const floatx2 gv = {acc[2][2 * p], acc[2][2 * p + 1]};
    const floatx2 ov = {acc[3][2 * p], acc[3][2 * p + 1]};
    const floatx2 ei = exp2v(iv * -L2E);
    const floatx2 ef = exp2v(fv * -L2E);
    const floatx2 eg = exp2v(gv * (2.0f * L2E));
    const floatx2 eo = exp2v(ov * -L2E);
    const floatx2 A = ei + 1.0f;   // 1/sig(i)
    const floatx2 F = ef + 1.0f;   // 1/sig(f)
    const floatx2 Bg = eg + 1.0f;  // tanh(g) = (eg-1)/Bg
    const floatx2 P = A * Bg;
    const floatx2 num = c2[p] * P + (eg - 1.0f) * F;
    const floatx2 cn = num * rcp2(F * P);
    c2[p] = cn;
    const floatx2 ec = exp2v(cn * (2.0f * L2E));
    const floatx2 h = (ec - 1.0f) * rcp2((eo + 1.0f) * (ec + 1.0f));
    hpk[p] = (u32)f2bf(h.x) | ((u32)f2bf(h.y) << 16);
  }
  *(u32x2*)(wrh + s * 64 + (((wv * 2 + (q >> 1)) ^ sw) * 8) + (q & 1) * 4) =
      u32x2{hpk[0], hpk[1]};
}

// One fully-folded cell step over 4 n-tiles (64 samples): gates = h @ W_hh^T
// + (p0*A0 + p1*A1 + bias). Pos term via 1 extra MFMA per gate-group
// (zero-padded K) on the matrix pipe. 12 MFMAs per n-tile, 48 per step.
__device__ __forceinline__ void cell_step_fold(
    const u16* __restrict__ rdh, u16* __restrict__ wrh,
    const short8 (&afh)[4][2], const short8 (&xf)[4],
    const float* __restrict__ biasrow, const float* __restrict__ posrow,
    floatx2 (&c)[4][2], int q, int l16, int wv, int u0) {
#pragma unroll
  for (int n = 0; n < 4; ++n) {
    const int s = n * 16 + l16, sw = s & 7;
    const u16* hr = rdh + s * 64;
    const short8 hb0 = *(const short8*)(hr + ((q ^ sw) * 8));
    const short8 hb1 = *(const short8*)(hr + (((q + 4) ^ sw) * 8));
    const floatx2 pp = *(const floatx2*)(posrow + s * 2);
    short8 pf = short8{0, 0, 0, 0, 0, 0, 0, 0};
    if (q == 0) {
      pf[0] = (short)f2bf(pp.x);
      pf[1] = (short)f2bf(pp.y);
    }
    floatx4 acc[4];
#pragma unroll
    for (int t = 0; t < 4; ++t) {
      const floatx4 bias = *(const floatx4*)(biasrow + t * 64 + u0 + q * 4);
      acc[t] = mfma_bf(xf[t], pf, bias);  // pos term, no h dependence
    }
#pragma unroll
    for (int t = 0; t < 4; ++t) acc[t] = mfma_bf(afh[t][0], hb0, acc[t]);
#pragma unroll
    for (int t = 0; t < 4; ++t) acc[t] = mfma_bf(afh[t][1], hb1, acc[t]);
    nonlin_store(acc, c[n], wrh, s, q, wv);
  }
}

// Folded decoder step (j>=1) over 4 n-tiles: gates = h @ W_eff^T + b_eff
// (K=64, 8 MFMAs/n). n-loop serialized (acc[4]) to cap peak regs. rel_{j-1}
// via 2 MFMAs on xf[0..1] (rows 0/1 = h2p rows): wave wv covers tile n==wv.
// rel -> LDS (no vmcnt drain at barriers).
__device__ __forceinline__ void dec_step_folded(
    const u16* __restrict__ rdh, u16* __restrict__ wrh,
    const short8 (&af)[4][2], const short8 (&xf)[4],
    const float* __restrict__ biasrow, float b2p0, float b2p1,
    float* __restrict__ relrow,
    floatx2 (&c)[4][2], int q, int l16, int wv, int u0) {
#pragma unroll
  for (int n = 0; n < 4; ++n) {
    const int s = n * 16 + l16, sw = s & 7;
    const u16* hr = rdh + s * 64;
    const short8 hb0 = *(const short8*)(hr + ((q ^ sw) * 8));
    const short8 hb1 = *(const short8*)(hr + (((q + 4) ^ sw) * 8));
    floatx4 acc[4];
#pragma unroll
    for (int t = 0; t < 4; ++t) {
      const floatx4 bias = *(const floatx4*)(biasrow + t * 64 + u0 + q * 4);
      acc[t] = mfma_bf(af[t][0], hb0, bias);
    }
#pragma unroll
    for (int t = 0; t < 4; ++t) acc[t] = mfma_bf(af[t][1], hb1, acc[t]);
    if (wv == n) {  // 2 rel MFMAs on the idle matrix pipe; rows 0,1 -> q==0
      floatx4 ar = mfma_bf(xf[0], hb0, floatx4{0.f, 0.f, 0.f, 0.f});
      ar = mfma_bf(xf[1], hb1, ar);
      if (q == 0)
        *(floatx2*)(relrow + s * 2) = floatx2{ar[0] + b2p0, ar[1] + b2p1};
    }
    nonlin_store(acc, c[n], wrh, s, q, wv);
  }
}

// TILE_B=64, 1024 blocks = EXACTLY 4 blocks/CU in one resident generation
// (zero tail, no generation churn). Per step each wave runs 4 n-tiles: 2x the
// work per barrier at constant per-step fixed cost (barrier + chain latency),
// halving the stall fraction. R5 lesson: the 39MB WRITE spill is ~16 dwords
// per thread ONCE (not per step) -- tolerable; thread count halves it again.
__global__ void __launch_bounds__(NTHREADS, 4)
lstm_kernel(const float* __restrict__ obs_rel,
            const float* __restrict__ enc_emb_w, const float* __restrict__ enc_emb_b,
            const float* __restrict__ enc_w_ih, const float* __restrict__ enc_w_hh,
            const float* __restrict__ enc_b_ih, const float* __restrict__ enc_b_hh,
            const float* __restrict__ dec_emb_w, const float* __restrict__ dec_emb_b,
            const float* __restrict__ dec_w_ih, const float* __restrict__ dec_w_hh,
            const float* __restrict__ dec_b_ih, const float* __restrict__ dec_b_hh,
            const float* __restrict__ h2p_w, const float* __restrict__ h2p_b,
            float* __restrict__ out, int batch) {
  __shared__ __align__(16) u16 hS[2][TILE_B * 64];
  __shared__ __align__(16) float posS[OBS_LEN][TILE_B * 2];
  __shared__ __align__(16) float biasS[3][256];  // enc, dec0, dec-folded (f32)
  __shared__ __align__(16) float eA0[256], eA1[256];  // encoder rank-2 factors
  __shared__ __align__(16) float dA0[256], dA1[256];  // decoder rank-2 factors
  __shared__ __align__(16) float hw0S[64], hw1S[64];  // h2p_w rows, f32
  __shared__ __align__(16) float relS[PRED_LEN][TILE_B * 2];  // rel staging

  const int tid = threadIdx.x;
  const int wv = tid >> 6, lane = tid & 63;
  const int q = lane >> 4, l16 = lane & 15;
  const int u0 = wv << 4;
  const long S0 = (long)blockIdx.x * TILE_B;

  {  // stage all 8 encoder-step position rows (coalesced): 256 floatx4
    const int t = tid >> 5, i = tid & 31;
    *(floatx4*)&posS[t][i * 4] =
        *(const floatx4*)(obs_rel + (long)t * batch * 2 + S0 * 2 + i * 4);
  }
  if (tid < 64) {
    hw0S[tid] = h2p_w[tid];        // f32: W_eff build + rel-frag source
    hw1S[tid] = h2p_w[64 + tid];
  }
  {
    float A0, A1, B0;
    fold_rank2(enc_w_ih + tid * 64, enc_emb_w, enc_emb_b, A0, A1, B0);
    eA0[tid] = A0;
    eA1[tid] = A1;
    biasS[0][tid] = enc_b_ih[tid] + enc_b_hh[tid] + B0;
    fold_rank2(dec_w_ih + tid * 64, dec_emb_w, dec_emb_b, A0, A1, B0);
    dA0[tid] = A0;
    dA1[tid] = A1;
    const float db = dec_b_ih[tid] + dec_b_hh[tid] + B0;
    biasS[1][tid] = db;                                   // dec step 0
    biasS[2][tid] = db + A0 * h2p_b[0] + A1 * h2p_b[1];   // folded steps
  }
  for (int i = tid; i < TILE_B * 64 / 2; i += NTHREADS) ((u32*)&hS[0][0])[i] = 0;

  short8 afh[4][2], xf[4];   // xf = pos-term frags (enc/dec0) then rel frags
  floatx2 c[4][2];
  load_afrags(enc_w_hh, afh, u0, q, l16);
#pragma unroll
  for (int n = 0; n < 4; ++n) c[n][0] = c[n][1] = floatx2{0.f, 0.f};
  const float b2p0 = h2p_b[0], b2p1 = h2p_b[1];
  __syncthreads();  // posS + tables + bias + fold factors + h0 visible
  build_gfrag(eA0, eA1, xf, u0, q, l16);

  int pb = 0;
#pragma unroll 1
  for (int t = 0; t < OBS_LEN; ++t) {
    cell_step_fold(hS[pb], hS[pb ^ 1], afh, xf, &biasS[0][0], &posS[t][0], c,
                   q, l16, wv, u0);
    __syncthreads();
    pb ^= 1;
  }

  // ---- decoder step 0: x0 = lin(pos7) folded with dec tables, c reset
  load_afrags(dec_w_hh, afh, u0, q, l16);
  build_gfrag(dA0, dA1, xf, u0, q, l16);
#pragma unroll
  for (int n = 0; n < 4; ++n) c[n][0] = c[n][1] = floatx2{0.f, 0.f};
  cell_step_fold(hS[pb], hS[pb ^ 1], afh, xf, &biasS[1][0], &posS[7][0], c,
                 q, l16, wv, u0);
  // rebuild afh as W_eff fragments for the h-feedback fold
  load_afrags_eff(dec_w_hh, dA0, dA1, hw0S, hw1S, afh, u0, q, l16);
  // xf[0..1] become the rel A-fragment: rows 0/1 = h2p rows (bf16), rest 0
#pragma unroll
  for (int kf = 0; kf < 2; ++kf) {
    const int kb = kf * 32 + q * 8;
    short8 a;
#pragma unroll
    for (int j = 0; j < 4; ++j) {
      const float r0 = (l16 == 0) ? hw0S[kb + j] : (l16 == 1) ? hw1S[kb + j] : 0.f;
      const float r1 =
          (l16 == 0) ? hw0S[kb + 4 + j] : (l16 == 1) ? hw1S[kb + 4 + j] : 0.f;
      a[j] = (short)f2bf(r0);
      a[j + 4] = (short)f2bf(r1);
    }
    xf[kf] = a;
  }
  __syncthreads();
  pb ^= 1;

  // ---- folded decoder steps 1..11: one barrier each; rel_{j-1} via MFMA
#pragma unroll 1
  for (int j = 1; j < PRED_LEN; ++j) {
    dec_step_folded(hS[pb], hS[pb ^ 1], afh, xf, &biasS[2][0], b2p0, b2p1,
                    &relS[j - 1][0], c, q, l16, wv, u0);
    __syncthreads();  // h_{j+1} ready; hS[pb] reads done before next overwrite
    pb ^= 1;
  }

  // ---- trailing output: rel_pos[11] from h_12 (2 MFMAs, wave wv = tile wv)
  {
    const int s = wv * 16 + l16, sw = s & 7;
    const u16* hr = hS[pb] + s * 64;
    const short8 ha = *(const short8*)(hr + ((q ^ sw) * 8));
    const short8 hc = *(const short8*)(hr + (((q + 4) ^ sw) * 8));
    floatx4 ar = mfma_bf(xf[0], ha, floatx4{0.f, 0.f, 0.f, 0.f});
    ar = mfma_bf(xf[1], hc, ar);
    if (q == 0)
      *(floatx2*)(&relS[PRED_LEN - 1][s * 2]) =
          floatx2{ar[0] + b2p0, ar[1] + b2p1};
  }
  __syncthreads();

  // ---- flush relS -> out, fully coalesced (6 f32/thread)
#pragma unroll
  for (int r = 0; r < 6; ++r) {
    const int f = tid + r * 256;          // 0..1535 = 12 rows x 128 f32
    const int j = f >> 7, e = f & 127;
    out[(long)j * batch * 2 + S0 * 2 + e] = ((const float*)relS)[f];
  }
}

extern "C" void kernel_launch(void* const* d_in, const int* in_sizes, int n_in,
                              void* d_out, int out_size, void* d_ws, size_t ws_size,
                              hipStream_t stream) {
  const float* obs_rel = (const float*)d_in[1];
  const int batch = in_sizes[1] / (OBS_LEN * 2);  // 65536

  const int blocks = batch / TILE_B;  // 1024 = exactly 4 blocks per CU
  hipLaunchKernelGGL(lstm_kernel, dim3(blocks), dim3(NTHREADS), 0, stream,
                     obs_rel,
                     (const float*)d_in[2], (const float*)d_in[3],
                     (const float*)d_in[4], (const float*)d_in[5],
                     (const float*)d_in[6], (const float*)d_in[7],
                     (const float*)d_in[8], (const float*)d_in[9],
                     (const float*)d_in[10], (const float*)d_in[11],
                     (const float*)d_in[12], (const float*)d_in[13],
                     (const float*)d_in[14], (const float*)d_in[15],
                     (float*)d_out, batch);
}

// Round 7
// 197.702 us; speedup vs baseline: 1.0854x; 1.0119x over previous
//
#include <hip/hip_runtime.h>

#define OBS_LEN 8
#define PRED_LEN 12
#define TILE_B 64
#define NTHREADS 256

typedef __attribute__((ext_vector_type(8))) short short8;  // 8 bf16
typedef __attribute__((ext_vector_type(4))) float floatx4;
typedef __attribute__((ext_vector_type(2))) float floatx2;
typedef __attribute__((ext_vector_type(4))) unsigned int u32x4;
typedef __attribute__((ext_vector_type(2))) unsigned int u32x2;
typedef unsigned short u16;
typedef unsigned int u32;

#define L2E 1.442695040888963f

__device__ __forceinline__ u16 f2bf(float f) {
  __bf16 b = (__bf16)f;
  return __builtin_bit_cast(u16, b);
}

#if __has_builtin(__builtin_amdgcn_exp2f)
__device__ __forceinline__ float fexp2_(float x) { return __builtin_amdgcn_exp2f(x); }
#else
__device__ __forceinline__ float fexp2_(float x) { return exp2f(x); }
#endif
__device__ __forceinline__ floatx2 exp2v(floatx2 x) {
  floatx2 r;
  r.x = fexp2_(x.x);
  r.y = fexp2_(x.y);
  return r;
}
#if __has_builtin(__builtin_amdgcn_rcpf)
__device__ __forceinline__ floatx2 rcp2(floatx2 x) {  // raw v_rcp ~1ulp
  floatx2 r;
  r.x = __builtin_amdgcn_rcpf(x.x);
  r.y = __builtin_amdgcn_rcpf(x.y);
  return r;
}
#else
__device__ __forceinline__ floatx2 rcp2(floatx2 x) {
  return floatx2{1.0f / x.x, 1.0f / x.y};
}
#endif

__device__ __forceinline__ floatx4 mfma_bf(short8 a, short8 b, floatx4 c) {
  return __builtin_amdgcn_mfma_f32_16x16x32_bf16(a, b, c, 0, 0, 0);
}

// short8 with elements 0,1 = the two bf16 halves of a, rest zero (k=0,1 frag).
__device__ __forceinline__ short8 frag_lo(u32 a) {
  return __builtin_bit_cast(short8, u32x4{a, 0u, 0u, 0u});
}

// Rank-2 input fold for gate row g: A_r[g] = sum_e W_ih[g,e]*emb_w[e,r],
// B0[g] = sum_e W_ih[g,e]*emb_b[e].
__device__ __forceinline__ void fold_rank2(const float* __restrict__ wr,
                                           const float* __restrict__ emb_w,
                                           const float* __restrict__ emb_b,
                                           float& A0, float& A1, float& B0) {
  A0 = A1 = B0 = 0.f;
#pragma unroll
  for (int e4 = 0; e4 < 16; ++e4) {
    const floatx4 w = *(const floatx4*)(wr + e4 * 4);
    const floatx4 m0 = *(const floatx4*)(emb_w + e4 * 8);      // e0,e1 pairs
    const floatx4 m1 = *(const floatx4*)(emb_w + e4 * 8 + 4);  // e2,e3 pairs
    const floatx4 bb = *(const floatx4*)(emb_b + e4 * 4);
    A0 += w[0] * m0[0] + w[1] * m0[2] + w[2] * m1[0] + w[3] * m1[2];
    A1 += w[0] * m0[1] + w[1] * m0[3] + w[2] * m1[1] + w[3] * m1[3];
    B0 += w[0] * bb[0] + w[1] * bb[1] + w[2] * bb[2] + w[3] * bb[3];
  }
}

// Stage W (f32 row-major [256][64]) into frag-ready LDS: slot (tile,kf,lane)
// holds A-frag 16B for row=lane&15 of tile, k = kf*32 + (lane>>4)*8 + j.
// Read side is wS + lane*16 + imm -> sequential, conflict-free ds_read_b128.
__device__ __forceinline__ void stage_w(const float* __restrict__ W,
                                        u16* __restrict__ wS, int tid) {
#pragma unroll
  for (int i = 0; i < 8; ++i) {
    const int slot = tid + i * 256;
    const int lane = slot & 63, kf = (slot >> 6) & 1, tile = slot >> 7;
    const int g = lane >> 4, l16 = lane & 15;
    const int gate = (tile >> 2) * 64 + (tile & 3) * 16 + l16;
    const float* src = W + gate * 64 + kf * 32 + g * 8;
    const floatx4 w0 = *(const floatx4*)src;
    const floatx4 w1 = *(const floatx4*)(src + 4);
    short8 a;
#pragma unroll
    for (int j = 0; j < 4; ++j) {
      a[j] = (short)f2bf(w0[j]);
      a[j + 4] = (short)f2bf(w1[j]);
    }
    *(short8*)(wS + slot * 8) = a;
  }
}

// Same, but W_eff = Whh + A0⊗h2p0 + A1⊗h2p1 (f32 math, ONE bf16 rounding).
__device__ __forceinline__ void stage_weff(const float* __restrict__ Whh,
                                           const float* __restrict__ dA0S,
                                           const float* __restrict__ dA1S,
                                           const float* __restrict__ hw0,
                                           const float* __restrict__ hw1,
                                           u16* __restrict__ wS, int tid) {
#pragma unroll
  for (int i = 0; i < 8; ++i) {
    const int slot = tid + i * 256;
    const int lane = slot & 63, kf = (slot >> 6) & 1, tile = slot >> 7;
    const int g = lane >> 4, l16 = lane & 15;
    const int gate = (tile >> 2) * 64 + (tile & 3) * 16 + l16;
    const int k0 = kf * 32 + g * 8;
    const float a0 = dA0S[gate], a1 = dA1S[gate];
    const float* src = Whh + gate * 64 + k0;
    const floatx4 w0 = *(const floatx4*)src;
    const floatx4 w1 = *(const floatx4*)(src + 4);
    const floatx4 p00 = *(const floatx4*)(hw0 + k0);
    const floatx4 p01 = *(const floatx4*)(hw0 + k0 + 4);
    const floatx4 p10 = *(const floatx4*)(hw1 + k0);
    const floatx4 p11 = *(const floatx4*)(hw1 + k0 + 4);
    short8 a;
#pragma unroll
    for (int j = 0; j < 4; ++j) {
      a[j] = (short)f2bf(w0[j] + a0 * p00[j] + a1 * p10[j]);
      a[j + 4] = (short)f2bf(w1[j] + a0 * p01[j] + a1 * p11[j]);
    }
    *(short8*)(wS + slot * 8) = a;
  }
}

// Gate nonlinearity + wave-private swizzled h write for one ut-group
// (verbatim math from the proven kernel; cc = cell state, units ut*16+4g+r).
__device__ __forceinline__ void nonlin_store_ut(const floatx4 (&acc)[4],
                                                floatx4& cc,
                                                u16* __restrict__ wrh,
                                                int l16, int g, int ut) {
  const int sw = l16 & 7;
  u32 hpk[2];
#pragma unroll
  for (int p = 0; p < 2; ++p) {
    const floatx2 iv = {acc[0][2 * p], acc[0][2 * p + 1]};
    const floatx2 fv = {acc[1][2 * p], acc[1][2 * p + 1]};
    const floatx2 gv = {acc[2][2 * p], acc[2][2 * p + 1]};
    const floatx2 ov = {acc[3][2 * p], acc[3][2 * p + 1]};
    const floatx2 ei = exp2v(iv * -L2E);
    const floatx2 ef = exp2v(fv * -L2E);
    const floatx2 eg = exp2v(gv * (2.0f * L2E));
    const floatx2 eo = exp2v(ov * -L2E);
    const floatx2 A = ei + 1.0f;   // 1/sig(i)
    const floatx2 F = ef + 1.0f;   // 1/sig(f)
    const floatx2 Bg = eg + 1.0f;  // tanh(g) = (eg-1)/Bg
    const floatx2 P = A * Bg;
    const floatx2 cold = {cc[2 * p], cc[2 * p + 1]};
    const floatx2 num = cold * P + (eg - 1.0f) * F;
    const floatx2 cn = num * rcp2(F * P);
    cc[2 * p] = cn.x;
    cc[2 * p + 1] = cn.y;
    const floatx2 ec = exp2v(cn * (2.0f * L2E));
    const floatx2 h = (ec - 1.0f) * rcp2((eo + 1.0f) * (ec + 1.0f));
    hpk[p] = (u32)f2bf(h.x) | ((u32)f2bf(h.y) << 16);
  }
  *(u32x2*)(wrh + l16 * 64 + (((ut * 2 + (g >> 1)) ^ sw) * 8) + (g & 1) * 4) =
      u32x2{hpk[0], hpk[1]};
}

// One ut-group (units ut*16..+15, this wave's 16 samples): 4 gate-tiles,
// gates = h @ W^T (+ pos rank-2 term when PH==0) + bias. W-frags stream from
// LDS (fixed addrs, off the dependency chain). PH: 0 = pos-term (enc/dec0),
// 1 = folded decoder (no pos term).
template <int PH>
__device__ __forceinline__ void ut_group(int ut, floatx4& cc,
                                         short8 hb0, short8 hb1, short8 pfv,
                                         const u16* __restrict__ wp,
                                         const u32* __restrict__ pafp,
                                         const float* __restrict__ biasp,
                                         u16* __restrict__ wrh,
                                         int g, int l16) {
  floatx4 acc[4];
#pragma unroll
  for (int tg = 0; tg < 4; ++tg) {
    const int tile = tg * 4 + ut;
    const floatx4 biasv = *(const floatx4*)(biasp + tg * 64 + ut * 16 + g * 4);
    if (PH == 0) {
      const u32 pa = (g == 0) ? pafp[tile * 16 + l16] : 0u;
      acc[tg] = mfma_bf(frag_lo(pa), pfv, biasv);  // pos term on matrix pipe
    } else {
      acc[tg] = biasv;
    }
    acc[tg] = mfma_bf(*(const short8*)(wp + (tile * 2 + 1) * 512), hb1, acc[tg]);
    acc[tg] = mfma_bf(*(const short8*)(wp + (tile * 2 + 0) * 512), hb0, acc[tg]);
  }
  nonlin_store_ut(acc, cc, wrh, l16, g, ut);
}

// Sample-ownership: each wave owns 16 samples and computes ALL 256 gates for
// them; h lives in a wave-PRIVATE 2KB LDS strip -> NO __syncthreads in any of
// the 21 recurrence steps (only ~4 at weight-stage transitions). Weights are
// streamed from frag-formatted LDS (32KB). 12 independent wave-chains/CU at
// (256,3) feed the VALU (75us floor) without barrier lockstep.
__global__ void __launch_bounds__(NTHREADS, 3)
lstm_kernel(const float* __restrict__ obs_rel,
            const float* __restrict__ enc_emb_w, const float* __restrict__ enc_emb_b,
            const float* __restrict__ enc_w_ih, const float* __restrict__ enc_w_hh,
            const float* __restrict__ enc_b_ih, const float* __restrict__ enc_b_hh,
            const float* __restrict__ dec_emb_w, const float* __restrict__ dec_emb_b,
            const float* __restrict__ dec_w_ih, const float* __restrict__ dec_w_hh,
            const float* __restrict__ dec_b_ih, const float* __restrict__ dec_b_hh,
            const float* __restrict__ h2p_w, const float* __restrict__ h2p_b,
            float* __restrict__ out, int batch) {
  __shared__ __align__(16) u16 wS[16384];          // 32KB frag-formatted weights
  __shared__ __align__(16) u16 hP[4 * 1024];       // 8KB wave-private h strips
  __shared__ __align__(16) float biasS[3][256];    // enc, dec0, dec-folded
  __shared__ __align__(16) u32 pafS[2][256];       // packed (A0,A1) [tile][l16]
  __shared__ __align__(16) u32 posP[OBS_LEN * 64]; // packed bf16 pos pairs
  __shared__ __align__(16) float hw0S[64], hw1S[64];
  __shared__ __align__(16) float dA0S[256], dA1S[256];

  const int tid = threadIdx.x;
  const int wv = tid >> 6, lane = tid & 63;
  const int g = lane >> 4, l16 = lane & 15;
  const long S0 = (long)blockIdx.x * TILE_B;

  // ---- prologue staging
  for (int i = tid; i < OBS_LEN * 64; i += NTHREADS) {
    const int t = i >> 6, s = i & 63;
    const floatx2 pp = *(const floatx2*)(obs_rel + (long)t * batch * 2 + (S0 + s) * 2);
    posP[i] = (u32)f2bf(pp.x) | ((u32)f2bf(pp.y) << 16);
  }
  if (tid < 64) {
    hw0S[tid] = h2p_w[tid];
    hw1S[tid] = h2p_w[64 + tid];
  }
  const float hb2p0 = h2p_b[0], hb2p1 = h2p_b[1];
  {
    const int t = tid >> 6, u6 = tid & 63;
    const int pidx = (t * 4 + (u6 >> 4)) * 16 + (u6 & 15);
    float A0, A1, B0;
    fold_rank2(enc_w_ih + tid * 64, enc_emb_w, enc_emb_b, A0, A1, B0);
    pafS[0][pidx] = (u32)f2bf(A0) | ((u32)f2bf(A1) << 16);
    biasS[0][tid] = enc_b_ih[tid] + enc_b_hh[tid] + B0;
    fold_rank2(dec_w_ih + tid * 64, dec_emb_w, dec_emb_b, A0, A1, B0);
    pafS[1][pidx] = (u32)f2bf(A0) | ((u32)f2bf(A1) << 16);
    dA0S[tid] = A0;
    dA1S[tid] = A1;
    const float db = dec_b_ih[tid] + dec_b_hh[tid] + B0;
    biasS[1][tid] = db;                                  // dec step 0
    biasS[2][tid] = db + A0 * hb2p0 + A1 * hb2p1;        // folded steps
  }
  stage_w(enc_w_hh, wS, tid);
  for (int i = tid; i < 2048; i += NTHREADS) ((u32*)hP)[i] = 0;  // h0 = 0
  __syncthreads();

  u16* hw = hP + wv * 1024;             // this wave's private h strip
  const u16* wp = wS + lane * 8;        // frag base (lane*16 bytes)
  const int sw8 = l16 & 7;
  floatx4 c0{0.f, 0.f, 0.f, 0.f}, c1{0.f, 0.f, 0.f, 0.f};
  floatx4 c2v{0.f, 0.f, 0.f, 0.f}, c3{0.f, 0.f, 0.f, 0.f};

  // ---- encoder: 8 barrier-free steps
#pragma unroll 1
  for (int t = 0; t < OBS_LEN; ++t) {
    const u16* hr = hw + l16 * 64;
    const short8 hb0 = *(const short8*)(hr + ((g ^ sw8) * 8));
    const short8 hb1 = *(const short8*)(hr + (((4 + g) ^ sw8) * 8));
    const u32 pp = (g == 0) ? posP[t * 64 + wv * 16 + l16] : 0u;
    const short8 pfv = frag_lo(pp);
    ut_group<0>(0, c0, hb0, hb1, pfv, wp, &pafS[0][0], &biasS[0][0], hw, g, l16);
    __builtin_amdgcn_sched_barrier(0);
    ut_group<0>(1, c1, hb0, hb1, pfv, wp, &pafS[0][0], &biasS[0][0], hw, g, l16);
    __builtin_amdgcn_sched_barrier(0);
    ut_group<0>(2, c2v, hb0, hb1, pfv, wp, &pafS[0][0], &biasS[0][0], hw, g, l16);
    __builtin_amdgcn_sched_barrier(0);
    ut_group<0>(3, c3, hb0, hb1, pfv, wp, &pafS[0][0], &biasS[0][0], hw, g, l16);
  }

  // ---- decoder step 0: x0 = lin(pos7), plain W_hh_dec, c reset
  __syncthreads();                     // all waves done with W_enc
  stage_w(dec_w_hh, wS, tid);
  __syncthreads();
  c0 = c1 = c2v = c3 = floatx4{0.f, 0.f, 0.f, 0.f};
  {
    const u16* hr = hw + l16 * 64;
    const short8 hb0 = *(const short8*)(hr + ((g ^ sw8) * 8));
    const short8 hb1 = *(const short8*)(hr + (((4 + g) ^ sw8) * 8));
    const u32 pp = (g == 0) ? posP[7 * 64 + wv * 16 + l16] : 0u;
    const short8 pfv = frag_lo(pp);
    ut_group<0>(0, c0, hb0, hb1, pfv, wp, &pafS[1][0], &biasS[1][0], hw, g, l16);
    __builtin_amdgcn_sched_barrier(0);
    ut_group<0>(1, c1, hb0, hb1, pfv, wp, &pafS[1][0], &biasS[1][0], hw, g, l16);
    __builtin_amdgcn_sched_barrier(0);
    ut_group<0>(2, c2v, hb0, hb1, pfv, wp, &pafS[1][0], &biasS[1][0], hw, g, l16);
    __builtin_amdgcn_sched_barrier(0);
    ut_group<0>(3, c3, hb0, hb1, pfv, wp, &pafS[1][0], &biasS[1][0], hw, g, l16);
  }
  __syncthreads();                     // all waves done reading W_dec
  stage_weff(dec_w_hh, dA0S, dA1S, hw0S, hw1S, wS, tid);
  __syncthreads();

  // rel A-fragments: rows 0/1 = h2p rows (bf16), rest zero
  short8 xf0, xf1;
#pragma unroll
  for (int kf = 0; kf < 2; ++kf) {
    const int kb = kf * 32 + g * 8;
    short8 a;
#pragma unroll
    for (int j = 0; j < 8; ++j) {
      const float r = (l16 == 0) ? hw0S[kb + j] : (l16 == 1) ? hw1S[kb + j] : 0.f;
      a[j] = (short)f2bf(r);
    }
    if (kf == 0) xf0 = a; else xf1 = a;
  }

  // ---- folded decoder steps 1..11: barrier-free; rel_{j-1} straight to HBM
  const floatx4 zero4{0.f, 0.f, 0.f, 0.f};
#pragma unroll 1
  for (int j = 1; j < PRED_LEN; ++j) {
    const u16* hr = hw + l16 * 64;
    const short8 hb0 = *(const short8*)(hr + ((g ^ sw8) * 8));
    const short8 hb1 = *(const short8*)(hr + (((4 + g) ^ sw8) * 8));
    floatx4 ar = mfma_bf(xf0, hb0, zero4);
    ar = mfma_bf(xf1, hb1, ar);
    if (g == 0)
      *(floatx2*)(out + (long)(j - 1) * batch * 2 + (S0 + wv * 16 + l16) * 2) =
          floatx2{ar[0] + hb2p0, ar[1] + hb2p1};
    ut_group<1>(0, c0, hb0, hb1, xf0, wp, &pafS[1][0], &biasS[2][0], hw, g, l16);
    __builtin_amdgcn_sched_barrier(0);
    ut_group<1>(1, c1, hb0, hb1, xf0, wp, &pafS[1][0], &biasS[2][0], hw, g, l16);
    __builtin_amdgcn_sched_barrier(0);
    ut_group<1>(2, c2v, hb0, hb1, xf0, wp, &pafS[1][0], &biasS[2][0], hw, g, l16);
    __builtin_amdgcn_sched_barrier(0);
    ut_group<1>(3, c3, hb0, hb1, xf0, wp, &pafS[1][0], &biasS[2][0], hw, g, l16);
  }

  // ---- trailing output: rel_11 from h_12
  {
    const u16* hr = hw + l16 * 64;
    const short8 hb0 = *(const short8*)(hr + ((g ^ sw8) * 8));
    const short8 hb1 = *(const short8*)(hr + (((4 + g) ^ sw8) * 8));
    floatx4 ar = mfma_bf(xf0, hb0, zero4);
    ar = mfma_bf(xf1, hb1, ar);
    if (g == 0)
      *(floatx2*)(out + (long)(PRED_LEN - 1) * batch * 2 + (S0 + wv * 16 + l16) * 2) =
          floatx2{ar[0] + hb2p0, ar[1] + hb2p1};
  }
}

extern "C" void kernel_launch(void* const* d_in, const int* in_sizes, int n_in,
                              void* d_out, int out_size, void* d_ws, size_t ws_size,
                              hipStream_t stream) {
  const float* obs_rel = (const float*)d_in[1];
  const int batch = in_sizes[1] / (OBS_LEN * 2);  // 65536

  const int blocks = batch / TILE_B;  // 1024
  hipLaunchKernelGGL(lstm_kernel, dim3(blocks), dim3(NTHREADS), 0, stream,
                     obs_rel,
                     (const float*)d_in[2], (const float*)d_in[3],
                     (const float*)d_in[4], (const float*)d_in[5],
                     (const float*)d_in[6], (const float*)d_in[7],
                     (const float*)d_in[8], (const float*)d_in[9],
                     (const float*)d_in[10], (const float*)d_in[11],
                     (const float*)d_in[12], (const float*)d_in[13],
                     (const float*)d_in[14], (const float*)d_in[15],
                     (float*)d_out, batch);
}

// Round 8
// 196.366 us; speedup vs baseline: 1.0928x; 1.0068x over previous
//
#include <hip/hip_runtime.h>

#define OBS_LEN 8
#define PRED_LEN 12
#define TILE_B 128
#define NTHREADS 512

typedef __attribute__((ext_vector_type(8))) short short8;  // 8 bf16
typedef __attribute__((ext_vector_type(4))) float floatx4;
typedef __attribute__((ext_vector_type(2))) float floatx2;
typedef __attribute__((ext_vector_type(4))) unsigned int u32x4;
typedef __attribute__((ext_vector_type(2))) unsigned int u32x2;
typedef unsigned short u16;
typedef unsigned int u32;

#define L2E 1.442695040888963f

__device__ __forceinline__ u16 f2bf(float f) {
  __bf16 b = (__bf16)f;
  return __builtin_bit_cast(u16, b);
}

#if __has_builtin(__builtin_amdgcn_exp2f)
__device__ __forceinline__ float fexp2_(float x) { return __builtin_amdgcn_exp2f(x); }
#else
__device__ __forceinline__ float fexp2_(float x) { return exp2f(x); }
#endif
__device__ __forceinline__ floatx2 exp2v(floatx2 x) {
  floatx2 r;
  r.x = fexp2_(x.x);
  r.y = fexp2_(x.y);
  return r;
}
#if __has_builtin(__builtin_amdgcn_rcpf)
__device__ __forceinline__ floatx2 rcp2(floatx2 x) {  // raw v_rcp ~1ulp
  floatx2 r;
  r.x = __builtin_amdgcn_rcpf(x.x);
  r.y = __builtin_amdgcn_rcpf(x.y);
  return r;
}
#else
__device__ __forceinline__ floatx2 rcp2(floatx2 x) {
  return floatx2{1.0f / x.x, 1.0f / x.y};
}
#endif

__device__ __forceinline__ floatx4 mfma_bf(short8 a, short8 b, floatx4 c) {
  return __builtin_amdgcn_mfma_f32_16x16x32_bf16(a, b, c, 0, 0, 0);
}

// short8 with elements 0,1 = the two bf16 halves of a, rest zero (k=0,1 frag).
__device__ __forceinline__ short8 frag_lo(u32 a) {
  return __builtin_bit_cast(short8, u32x4{a, 0u, 0u, 0u});
}

// Rank-2 input fold for gate row g: A_r[g] = sum_e W_ih[g,e]*emb_w[e,r],
// B0[g] = sum_e W_ih[g,e]*emb_b[e].
__device__ __forceinline__ void fold_rank2(const float* __restrict__ wr,
                                           const float* __restrict__ emb_w,
                                           const float* __restrict__ emb_b,
                                           float& A0, float& A1, float& B0) {
  A0 = A1 = B0 = 0.f;
#pragma unroll
  for (int e4 = 0; e4 < 16; ++e4) {
    const floatx4 w = *(const floatx4*)(wr + e4 * 4);
    const floatx4 m0 = *(const floatx4*)(emb_w + e4 * 8);      // e0,e1 pairs
    const floatx4 m1 = *(const floatx4*)(emb_w + e4 * 8 + 4);  // e2,e3 pairs
    const floatx4 bb = *(const floatx4*)(emb_b + e4 * 4);
    A0 += w[0] * m0[0] + w[1] * m0[2] + w[2] * m1[0] + w[3] * m1[2];
    A1 += w[0] * m0[1] + w[1] * m0[3] + w[2] * m1[1] + w[3] * m1[3];
    B0 += w[0] * bb[0] + w[1] * bb[1] + w[2] * bb[2] + w[3] * bb[3];
  }
}

// Stage W (f32 row-major [256][64]) into frag-ready LDS: slot (tile,kf,lane)
// holds A-frag 16B for row=lane&15 of tile, k = kf*32 + (lane>>4)*8 + j.
// Read side is wS + lane*16 + imm -> sequential, conflict-free ds_read_b128.
__device__ __forceinline__ void stage_w(const float* __restrict__ W,
                                        u16* __restrict__ wS, int tid) {
  for (int slot = tid; slot < 2048; slot += NTHREADS) {
    const int lane = slot & 63, kf = (slot >> 6) & 1, tile = slot >> 7;
    const int g = lane >> 4, l16 = lane & 15;
    const int gate = (tile >> 2) * 64 + (tile & 3) * 16 + l16;
    const float* src = W + gate * 64 + kf * 32 + g * 8;
    const floatx4 w0 = *(const floatx4*)src;
    const floatx4 w1 = *(const floatx4*)(src + 4);
    short8 a;
#pragma unroll
    for (int j = 0; j < 4; ++j) {
      a[j] = (short)f2bf(w0[j]);
      a[j + 4] = (short)f2bf(w1[j]);
    }
    *(short8*)(wS + slot * 8) = a;
  }
}

// Same, but W_eff = Whh + A0⊗h2p0 + A1⊗h2p1 (f32 math, ONE bf16 rounding).
__device__ __forceinline__ void stage_weff(const float* __restrict__ Whh,
                                           const float* __restrict__ dA0S,
                                           const float* __restrict__ dA1S,
                                           const float* __restrict__ hw0,
                                           const float* __restrict__ hw1,
                                           u16* __restrict__ wS, int tid) {
  for (int slot = tid; slot < 2048; slot += NTHREADS) {
    const int lane = slot & 63, kf = (slot >> 6) & 1, tile = slot >> 7;
    const int g = lane >> 4, l16 = lane & 15;
    const int gate = (tile >> 2) * 64 + (tile & 3) * 16 + l16;
    const int k0 = kf * 32 + g * 8;
    const float a0 = dA0S[gate], a1 = dA1S[gate];
    const float* src = Whh + gate * 64 + k0;
    const floatx4 w0 = *(const floatx4*)src;
    const floatx4 w1 = *(const floatx4*)(src + 4);
    const floatx4 p00 = *(const floatx4*)(hw0 + k0);
    const floatx4 p01 = *(const floatx4*)(hw0 + k0 + 4);
    const floatx4 p10 = *(const floatx4*)(hw1 + k0);
    const floatx4 p11 = *(const floatx4*)(hw1 + k0 + 4);
    short8 a;
#pragma unroll
    for (int j = 0; j < 4; ++j) {
      a[j] = (short)f2bf(w0[j] + a0 * p00[j] + a1 * p10[j]);
      a[j + 4] = (short)f2bf(w1[j] + a0 * p01[j] + a1 * p11[j]);
    }
    *(short8*)(wS + slot * 8) = a;
  }
}

// Gate nonlinearity + wave-private swizzled h write for one ut-group
// (verbatim math from the proven kernel; cc = cell state, units ut*16+4g+r).
__device__ __forceinline__ void nonlin_store_ut(const floatx4 (&acc)[4],
                                                floatx4& cc,
                                                u16* __restrict__ wrh,
                                                int l16, int g, int ut) {
  const int sw = l16 & 7;
  u32 hpk[2];
#pragma unroll
  for (int p = 0; p < 2; ++p) {
    const floatx2 iv = {acc[0][2 * p], acc[0][2 * p + 1]};
    const floatx2 fv = {acc[1][2 * p], acc[1][2 * p + 1]};
    const floatx2 gv = {acc[2][2 * p], acc[2][2 * p + 1]};
    const floatx2 ov = {acc[3][2 * p], acc[3][2 * p + 1]};
    const floatx2 ei = exp2v(iv * -L2E);
    const floatx2 ef = exp2v(fv * -L2E);
    const floatx2 eg = exp2v(gv * (2.0f * L2E));
    const floatx2 eo = exp2v(ov * -L2E);
    const floatx2 A = ei + 1.0f;   // 1/sig(i)
    const floatx2 F = ef + 1.0f;   // 1/sig(f)
    const floatx2 Bg = eg + 1.0f;  // tanh(g) = (eg-1)/Bg
    const floatx2 P = A * Bg;
    const floatx2 cold = {cc[2 * p], cc[2 * p + 1]};
    const floatx2 num = cold * P + (eg - 1.0f) * F;
    const floatx2 cn = num * rcp2(F * P);
    cc[2 * p] = cn.x;
    cc[2 * p + 1] = cn.y;
    const floatx2 ec = exp2v(cn * (2.0f * L2E));
    const floatx2 h = (ec - 1.0f) * rcp2((eo + 1.0f) * (ec + 1.0f));
    hpk[p] = (u32)f2bf(h.x) | ((u32)f2bf(h.y) << 16);
  }
  *(u32x2*)(wrh + l16 * 64 + (((ut * 2 + (g >> 1)) ^ sw) * 8) + (g & 1) * 4) =
      u32x2{hpk[0], hpk[1]};
}

// One ut-group (units ut*16..+15, this wave's 16 samples): 4 gate-tiles,
// gates = h @ W^T (+ pos rank-2 term when PH==0) + bias. W-frags stream from
// LDS (fixed addrs, off the dependency chain). PH: 0 = pos-term (enc/dec0),
// 1 = folded decoder (no pos term).
template <int PH>
__device__ __forceinline__ void ut_group(int ut, floatx4& cc,
                                         short8 hb0, short8 hb1, short8 pfv,
                                         const u16* __restrict__ wp,
                                         const u32* __restrict__ pafp,
                                         const float* __restrict__ biasp,
                                         u16* __restrict__ wrh,
                                         int g, int l16) {
  floatx4 acc[4];
#pragma unroll
  for (int tg = 0; tg < 4; ++tg) {
    const int tile = tg * 4 + ut;
    const floatx4 biasv = *(const floatx4*)(biasp + tg * 64 + ut * 16 + g * 4);
    if (PH == 0) {
      const u32 pa = (g == 0) ? pafp[tile * 16 + l16] : 0u;
      acc[tg] = mfma_bf(frag_lo(pa), pfv, biasv);  // pos term on matrix pipe
    } else {
      acc[tg] = biasv;
    }
    acc[tg] = mfma_bf(*(const short8*)(wp + (tile * 2 + 1) * 512), hb1, acc[tg]);
    acc[tg] = mfma_bf(*(const short8*)(wp + (tile * 2 + 0) * 512), hb0, acc[tg]);
  }
  nonlin_store_ut(acc, cc, wrh, l16, g, ut);
}

// Sample-ownership (R7 structure, repartitioned): each wave owns 16 samples,
// h in a wave-PRIVATE 2KB LDS strip -> no __syncthreads in the 21 recurrence
// steps. R7 lesson: 50.7KB LDS at 256 threads = 3 blocks/CU vs 4 needed ->
// straggler generation at 1 block/CU (Occ 26%). Fix: 8 waves/block share the
// 32KB weight LDS -> TILE_B=128, 512 blocks = EXACTLY 2 blocks/CU, 16
// waves/CU, zero tail. Wave-level code and math unchanged.
__global__ void __launch_bounds__(NTHREADS, 4)
lstm_kernel(const float* __restrict__ obs_rel,
            const float* __restrict__ enc_emb_w, const float* __restrict__ enc_emb_b,
            const float* __restrict__ enc_w_ih, const float* __restrict__ enc_w_hh,
            const float* __restrict__ enc_b_ih, const float* __restrict__ enc_b_hh,
            const float* __restrict__ dec_emb_w, const float* __restrict__ dec_emb_b,
            const float* __restrict__ dec_w_ih, const float* __restrict__ dec_w_hh,
            const float* __restrict__ dec_b_ih, const float* __restrict__ dec_b_hh,
            const float* __restrict__ h2p_w, const float* __restrict__ h2p_b,
            float* __restrict__ out, int batch) {
  __shared__ __align__(16) u16 wS[16384];           // 32KB frag-formatted weights
  __shared__ __align__(16) u16 hP[8 * 1024];        // 16KB wave-private h strips
  __shared__ __align__(16) float biasS[3][256];     // enc, dec0, dec-folded
  __shared__ __align__(16) u32 pafS[2][256];        // packed (A0,A1) [tile][l16]
  __shared__ __align__(16) u32 posP[OBS_LEN * TILE_B];  // packed bf16 pos pairs
  __shared__ __align__(16) float hw0S[64], hw1S[64];
  __shared__ __align__(16) float dA0S[256], dA1S[256];

  const int tid = threadIdx.x;
  const int wv = tid >> 6, lane = tid & 63;
  const int g = lane >> 4, l16 = lane & 15;
  const long S0 = (long)blockIdx.x * TILE_B;

  // ---- prologue staging
  for (int i = tid; i < OBS_LEN * TILE_B; i += NTHREADS) {
    const int t = i >> 7, s = i & 127;
    const floatx2 pp = *(const floatx2*)(obs_rel + (long)t * batch * 2 + (S0 + s) * 2);
    posP[i] = (u32)f2bf(pp.x) | ((u32)f2bf(pp.y) << 16);
  }
  if (tid < 64) {
    hw0S[tid] = h2p_w[tid];
    hw1S[tid] = h2p_w[64 + tid];
  }
  const float hb2p0 = h2p_b[0], hb2p1 = h2p_b[1];
  if (tid < 256) {
    const int t = tid >> 6, u6 = tid & 63;
    const int pidx = (t * 4 + (u6 >> 4)) * 16 + (u6 & 15);
    float A0, A1, B0;
    fold_rank2(enc_w_ih + tid * 64, enc_emb_w, enc_emb_b, A0, A1, B0);
    pafS[0][pidx] = (u32)f2bf(A0) | ((u32)f2bf(A1) << 16);
    biasS[0][tid] = enc_b_ih[tid] + enc_b_hh[tid] + B0;
    fold_rank2(dec_w_ih + tid * 64, dec_emb_w, dec_emb_b, A0, A1, B0);
    pafS[1][pidx] = (u32)f2bf(A0) | ((u32)f2bf(A1) << 16);
    dA0S[tid] = A0;
    dA1S[tid] = A1;
    const float db = dec_b_ih[tid] + dec_b_hh[tid] + B0;
    biasS[1][tid] = db;                                  // dec step 0
    biasS[2][tid] = db + A0 * hb2p0 + A1 * hb2p1;        // folded steps
  }
  stage_w(enc_w_hh, wS, tid);
  for (int i = tid; i < 4096; i += NTHREADS) ((u32*)hP)[i] = 0;  // h0 = 0
  __syncthreads();

  u16* hw = hP + wv * 1024;             // this wave's private h strip
  const u16* wp = wS + lane * 8;        // frag base (lane*16 bytes)
  const int sw8 = l16 & 7;
  floatx4 c0{0.f, 0.f, 0.f, 0.f}, c1{0.f, 0.f, 0.f, 0.f};
  floatx4 c2v{0.f, 0.f, 0.f, 0.f}, c3{0.f, 0.f, 0.f, 0.f};

  // ---- encoder: 8 barrier-free steps
#pragma unroll 1
  for (int t = 0; t < OBS_LEN; ++t) {
    const u16* hr = hw + l16 * 64;
    const short8 hb0 = *(const short8*)(hr + ((g ^ sw8) * 8));
    const short8 hb1 = *(const short8*)(hr + (((4 + g) ^ sw8) * 8));
    const u32 pp = (g == 0) ? posP[t * TILE_B + wv * 16 + l16] : 0u;
    const short8 pfv = frag_lo(pp);
    ut_group<0>(0, c0, hb0, hb1, pfv, wp, &pafS[0][0], &biasS[0][0], hw, g, l16);
    __builtin_amdgcn_sched_barrier(0);
    ut_group<0>(1, c1, hb0, hb1, pfv, wp, &pafS[0][0], &biasS[0][0], hw, g, l16);
    __builtin_amdgcn_sched_barrier(0);
    ut_group<0>(2, c2v, hb0, hb1, pfv, wp, &pafS[0][0], &biasS[0][0], hw, g, l16);
    __builtin_amdgcn_sched_barrier(0);
    ut_group<0>(3, c3, hb0, hb1, pfv, wp, &pafS[0][0], &biasS[0][0], hw, g, l16);
  }

  // ---- decoder step 0: x0 = lin(pos7), plain W_hh_dec, c reset
  __syncthreads();                     // all waves done with W_enc
  stage_w(dec_w_hh, wS, tid);
  __syncthreads();
  c0 = c1 = c2v = c3 = floatx4{0.f, 0.f, 0.f, 0.f};
  {
    const u16* hr = hw + l16 * 64;
    const short8 hb0 = *(const short8*)(hr + ((g ^ sw8) * 8));
    const short8 hb1 = *(const short8*)(hr + (((4 + g) ^ sw8) * 8));
    const u32 pp = (g == 0) ? posP[7 * TILE_B + wv * 16 + l16] : 0u;
    const short8 pfv = frag_lo(pp);
    ut_group<0>(0, c0, hb0, hb1, pfv, wp, &pafS[1][0], &biasS[1][0], hw, g, l16);
    __builtin_amdgcn_sched_barrier(0);
    ut_group<0>(1, c1, hb0, hb1, pfv, wp, &pafS[1][0], &biasS[1][0], hw, g, l16);
    __builtin_amdgcn_sched_barrier(0);
    ut_group<0>(2, c2v, hb0, hb1, pfv, wp, &pafS[1][0], &biasS[1][0], hw, g, l16);
    __builtin_amdgcn_sched_barrier(0);
    ut_group<0>(3, c3, hb0, hb1, pfv, wp, &pafS[1][0], &biasS[1][0], hw, g, l16);
  }
  __syncthreads();                     // all waves done reading W_dec
  stage_weff(dec_w_hh, dA0S, dA1S, hw0S, hw1S, wS, tid);
  __syncthreads();

  // rel A-fragments: rows 0/1 = h2p rows (bf16), rest zero
  short8 xf0, xf1;
#pragma unroll
  for (int kf = 0; kf < 2; ++kf) {
    const int kb = kf * 32 + g * 8;
    short8 a;
#pragma unroll
    for (int j = 0; j < 8; ++j) {
      const float r = (l16 == 0) ? hw0S[kb + j] : (l16 == 1) ? hw1S[kb + j] : 0.f;
      a[j] = (short)f2bf(r);
    }
    if (kf == 0) xf0 = a; else xf1 = a;
  }

  // ---- folded decoder steps 1..11: barrier-free; rel_{j-1} straight to HBM
  const floatx4 zero4{0.f, 0.f, 0.f, 0.f};
#pragma unroll 1
  for (int j = 1; j < PRED_LEN; ++j) {
    const u16* hr = hw + l16 * 64;
    const short8 hb0 = *(const short8*)(hr + ((g ^ sw8) * 8));
    const short8 hb1 = *(const short8*)(hr + (((4 + g) ^ sw8) * 8));
    floatx4 ar = mfma_bf(xf0, hb0, zero4);
    ar = mfma_bf(xf1, hb1, ar);
    if (g == 0)
      *(floatx2*)(out + (long)(j - 1) * batch * 2 + (S0 + wv * 16 + l16) * 2) =
          floatx2{ar[0] + hb2p0, ar[1] + hb2p1};
    ut_group<1>(0, c0, hb0, hb1, xf0, wp, &pafS[1][0], &biasS[2][0], hw, g, l16);
    __builtin_amdgcn_sched_barrier(0);
    ut_group<1>(1, c1, hb0, hb1, xf0, wp, &pafS[1][0], &biasS[2][0], hw, g, l16);
    __builtin_amdgcn_sched_barrier(0);
    ut_group<1>(2, c2v, hb0, hb1, xf0, wp, &pafS[1][0], &biasS[2][0], hw, g, l16);
    __builtin_amdgcn_sched_barrier(0);
    ut_group<1>(3, c3, hb0, hb1, xf0, wp, &pafS[1][0], &biasS[2][0], hw, g, l16);
  }

  // ---- trailing output: rel_11 from h_12
  {
    const u16* hr = hw + l16 * 64;
    const short8 hb0 = *(const short8*)(hr + ((g ^ sw8) * 8));
    const short8 hb1 = *(const short8*)(hr + (((4 + g) ^ sw8) * 8));
    floatx4 ar = mfma_bf(xf0, hb0, zero4);
    ar = mfma_bf(xf1, hb1, ar);
    if (g == 0)
      *(floatx2*)(out + (long)(PRED_LEN - 1) * batch * 2 + (S0 + wv * 16 + l16) * 2) =
          floatx2{ar[0] + hb2p0, ar[1] + hb2p1};
  }
}

extern "C" void kernel_launch(void* const* d_in, const int* in_sizes, int n_in,
                              void* d_out, int out_size, void* d_ws, size_t ws_size,
                              hipStream_t stream) {
  const float* obs_rel = (const float*)d_in[1];
  const int batch = in_sizes[1] / (OBS_LEN * 2);  // 65536

  const int blocks = batch / TILE_B;  // 512 = exactly 2 blocks per CU
  hipLaunchKernelGGL(lstm_kernel, dim3(blocks), dim3(NTHREADS), 0, stream,
                     obs_rel,
                     (const float*)d_in[2], (const float*)d_in[3],
                     (const float*)d_in[4], (const float*)d_in[5],
                     (const float*)d_in[6], (const float*)d_in[7],
                     (const float*)d_in[8], (const float*)d_in[9],
                     (const float*)d_in[10], (const float*)d_in[11],
                     (const float*)d_in[12], (const float*)d_in[13],
                     (const float*)d_in[14], (const float*)d_in[15],
                     (float*)d_out, batch);
}